// Round 8
// baseline (622.462 us; speedup 1.0000x reference)
//
#include <hip/hip_runtime.h>
#include <stdint.h>

#define KNN 48
#define CH  128

typedef __attribute__((ext_vector_type(8))) short bf16x8;
typedef __attribute__((ext_vector_type(4))) float f32x4;

__device__ __forceinline__ float bf2f(unsigned short u){
  union { unsigned int i; float f; } v; v.i = ((unsigned int)u) << 16; return v.f;
}
__device__ __forceinline__ unsigned short f2bf(float f){
  union { float f; unsigned int i; } v; v.f = f;
  unsigned int x = v.i;
  x += 0x7fffu + ((x >> 16) & 1u);
  return (unsigned short)(x >> 16);
}
template<int MODE>
__device__ __forceinline__ float ld1(const void* p, size_t i){
  if (MODE) return ((const float*)p)[i];
  return bf2f(((const unsigned short*)p)[i]);
}
template<int MODE>
__device__ __forceinline__ void vload4(float* o, const void* p, size_t i){
  if (MODE){
    float4 v = *(const float4*)((const float*)p + i);
    o[0] = v.x; o[1] = v.y; o[2] = v.z; o[3] = v.w;
  } else {
    uint2 v = *(const uint2*)((const unsigned short*)p + i);
    union { unsigned int u; float f; } a, b, c, d;
    a.u = v.x << 16; b.u = v.x & 0xFFFF0000u;
    c.u = v.y << 16; d.u = v.y & 0xFFFF0000u;
    o[0] = a.f; o[1] = b.f; o[2] = c.f; o[3] = d.f;
  }
}
__device__ __forceinline__ void lds_bf4(float* o, const unsigned short* p){
  uint2 v = *(const uint2*)p;
  union { unsigned int u; float f; } a, b, c, d;
  a.u = v.x << 16; b.u = v.x & 0xFFFF0000u;
  c.u = v.y << 16; d.u = v.y & 0xFFFF0000u;
  o[0] = a.f; o[1] = b.f; o[2] = c.f; o[3] = d.f;
}
__device__ __forceinline__ void sts_bf4(unsigned short* p, const float* v){
  unsigned int lo = (unsigned int)f2bf(v[0]) | ((unsigned int)f2bf(v[1]) << 16);
  unsigned int hi = (unsigned int)f2bf(v[2]) | ((unsigned int)f2bf(v[3]) << 16);
  uint2 w; w.x = lo; w.y = hi;
  *(uint2*)p = w;
}

// ---------------- dtype + mask-format detector (parallel scan) ----------------
__global__ __launch_bounds__(256) void detect_k(const void* qc, const void* kmask, int* hdr){
  __shared__ int cnt, flg;
  int t = threadIdx.x;
  if (t == 0){ cnt = 0; flg = 0; }
  __syncthreads();
  float v = bf2f(((const unsigned short*)qc)[t]);
  if (v >= 0.f && v <= 70.5f) atomicAdd(&cnt, 1);
  const unsigned int* mw = (const unsigned int*)kmask;
  int f = 0;
  for (int i = t; i < 384; i += 256){
    unsigned int w = mw[i];
    if (w != 0u && w != 1u) f |= 1;
    if (w != 0u && w != 0x3F800000u) f |= 2;
    if (w == 0x3F800000u) f |= 4;
    unsigned int lo = w & 0xFFFFu, hi = w >> 16;
    if ((lo != 0u && lo != 0x3F80u) || (hi != 0u && hi != 0x3F80u)) f |= 8;
    if (lo == 0x3F80u || hi == 0x3F80u) f |= 16;
  }
  if (f) atomicOr(&flg, f);
  __syncthreads();
  if (t == 0){
    int F = flg;
    hdr[0] = (cnt >= 240) ? 0 : 1;
    int fmt;
    if (!(F & 2) && (F & 4)) fmt = 3;
    else if (!(F & 8) && (F & 16)) fmt = 2;
    else if (!(F & 1)) fmt = 0;
    else fmt = 1;
    hdr[1] = fmt;
  }
}

// ---------------- attention: 8 queries/block, 256 threads, 8 SINGLE-query iterations ----------------
// R4-proven formulas with the q-pair dimension moved to the outer loop. LDS halves -> 5 blocks/CU.
// pool (bytes):
//   kf    bf16 [48][136] @0      13056   | prologue alias qfv8 f32 [8][132] 4224
//   qkhi  bf16 [8][136]  @13056  2176    (cc>=8 spill-reads into qklo/sa: harmless, rows discarded)
//   qklo  bf16 [8][136]  @15232  2176
//   af    f32  [8][132]  @13056  4224    (ALIAS of qk region; written in E after qk dead)
//   sa    f32  [416]     @17408  1664    (scores [8][52]; then V-partials [2][128])
//   qv8   f32  [8][132]  @19072  4224
//   wk3s  f32  [384]     @23296  1536
//   bk3s  f32  [128]     @24832  512
//   sb8   f32  [64]      @25344  256
//   rel   f32  [144]     @25600  576
//   mb    f32  [48]      @26176  192
//   idxs  int  [48]      @26368  192
//   qc8   f32  [24]      @26560  96
//   athi  bf16 [16][48]  @26656  1536    (rows 8-15 garbage-read by MFMA A: harmless)
//   atlo  bf16 [16][48]  @28192  1536    -> 29728 total (5 blocks/CU, 20 waves)
template<int MODE>
__device__ void attn_body(char* pool,
  const void* vf, const void* vc, const void* qc,
  const void* wq3, const void* bq3, const void* wk3, const void* bk3,
  const void* ipw, const void* ipb,
  const int* kidx, const void* kmask,
  unsigned short* O, int fmt)
{
  unsigned short* kf = (unsigned short*)(pool);
  float* qfv8 = (float*)(pool);
  unsigned short* qkhi = (unsigned short*)(pool + 13056);
  unsigned short* qklo = (unsigned short*)(pool + 15232);
  float* af   = (float*)(pool + 13056);
  float* sa   = (float*)(pool + 17408);
  float* qv8  = (float*)(pool + 19072);
  float* wk3s = (float*)(pool + 23296);
  float* bk3s = (float*)(pool + 24832);
  float* sb8  = (float*)(pool + 25344);
  float* rel  = (float*)(pool + 25600);
  float* mb   = (float*)(pool + 26176);
  int*   idxs = (int*)  (pool + 26368);
  float* qc8  = (float*)(pool + 26560);
  unsigned short* athi = (unsigned short*)(pool + 26656);
  unsigned short* atlo = (unsigned short*)(pool + 28192);

  int t = threadIdx.x;
  int qbase = blockIdx.x * 8;

  // A-phase for single query pp: threads tt in [0,48)
  auto doA = [&](int kk, int pp){
    int n = qbase + pp;
    int iv = kidx[(size_t)n * KNN + kk];
    idxs[kk] = iv;
    rel[kk * 3 + 0] = ld1<MODE>(vc, (size_t)iv * 3 + 0) - qc8[pp * 3 + 0];
    rel[kk * 3 + 1] = ld1<MODE>(vc, (size_t)iv * 3 + 1) - qc8[pp * 3 + 1];
    rel[kk * 3 + 2] = ld1<MODE>(vc, (size_t)iv * 3 + 2) - qc8[pp * 3 + 2];
    int mi = n * KNN + kk;
    int mval;
    if (fmt == 0)      mval = (((const int*)kmask)[mi] != 0);
    else if (fmt == 1) mval = (((const unsigned char*)kmask)[mi] != 0);
    else if (fmt == 2) mval = (((const unsigned short*)kmask)[mi] != 0);
    else               mval = (((const unsigned int*)kmask)[mi] != 0);
    mb[kk] = mval ? -1e9f : 0.f;
  };

  // prologue: small tables
  for (int i = t; i < 384; i += 256) wk3s[i] = ld1<MODE>(wk3, i);
  if (t < 128) bk3s[t] = ld1<MODE>(bk3, t);
  if (t < 24)  qc8[t]  = ld1<MODE>(qc, (size_t)qbase * 3 + t);
  __syncthreads();

  // A(0) + q_feat for 8 queries (qfv8 aliases kf region)
  if (t < 48) doA(t, 0);
  if (t < 128){
    float w0 = ld1<MODE>(wq3, t), w1 = ld1<MODE>(wq3, 128 + t);
    float w2 = ld1<MODE>(wq3, 256 + t), bb = ld1<MODE>(bq3, t);
    for (int q = 0; q < 8; ++q){
      float a = qc8[q * 3 + 0] * w0 + qc8[q * 3 + 1] * w1 + qc8[q * 3 + 2] * w2 + bb;
      qfv8[q * 132 + t] = fmaxf(a, 0.f);
    }
  }
  __syncthreads();

  // joint q-projection (4 queries per 128-thread half) -> qv8 persists all 8 iterations
  {
    int j = t & 127, qg = (t >> 7) * 4;
    float a0 = 0.f, a1 = 0.f, a2 = 0.f, a3 = 0.f;
    for (int c = 0; c < 128; c += 4){
      float w[4];
      vload4<MODE>(w, ipw, (size_t)j * CH + c);
      for (int u = 0; u < 4; ++u){
        float wv = w[u];
        a0 += qfv8[(qg + 0) * 132 + c + u] * wv;
        a1 += qfv8[(qg + 1) * 132 + c + u] * wv;
        a2 += qfv8[(qg + 2) * 132 + c + u] * wv;
        a3 += qfv8[(qg + 3) * 132 + c + u] * wv;
      }
    }
    float bb = ld1<MODE>(ipb, j);
    qv8[(qg + 0) * 132 + j] = (a0 + bb) * 0.25f;
    qv8[(qg + 1) * 132 + j] = (a1 + bb) * 0.25f;
    qv8[(qg + 2) * 132 + j] = (a2 + bb) * 0.25f;
    qv8[(qg + 3) * 132 + j] = (a3 + bb) * 0.25f;
  }
  __syncthreads();

  for (int p = 0; p < 8; ++p){
    // ---- B: G(p-1) / sb8; gather loads issued EARLY (T14); qk-proj; gather finish ----
    if (p == 0){
      if (t < 64){
        int q = t >> 3, h = t & 7;
        float sb = 0.f;
        for (int d = 0; d < 16; ++d) sb += qv8[q * 132 + h * 16 + d] * ld1<MODE>(ipb, 128 + h * 16 + d);
        sb8[t] = sb;
      }
    } else if (t < 128){
      float o = sa[t] + sa[128 + t] + ld1<MODE>(ipb, 256 + t);
      O[(size_t)(qbase + p - 1) * CH + t] = f2bf(o);
    }

    // stage 1: issue all 6 gather loads into registers
    float vbuf[6][4];
    #pragma unroll
    for (int it = 0; it < 6; ++it){
      int e4 = (it * 256 + t) * 4;
      int k = e4 >> 7, c = e4 & 127;
      int iv = idxs[k];
      vload4<MODE>(vbuf[it], vf, (size_t)iv * CH + c);
    }

    // qk projection (hi/lo bf16) for query p
    {
      int h = t >> 5, cb = (t & 31) << 2;
      float aa0 = 0.f, aa1 = 0.f, aa2 = 0.f, aa3 = 0.f;
      int qla = p * 132 + h * 16;
      for (int d = 0; d < 16; ++d){
        float w[4];
        vload4<MODE>(w, ipw, (size_t)(128 + h * 16 + d) * CH + cb);
        float qa = qv8[qla + d];
        aa0 += qa * w[0]; aa1 += qa * w[1]; aa2 += qa * w[2]; aa3 += qa * w[3];
      }
      unsigned short h0 = f2bf(aa0), h1 = f2bf(aa1), h2 = f2bf(aa2), h3 = f2bf(aa3);
      uint2 w0; w0.x = (unsigned)h0 | ((unsigned)h1 << 16); w0.y = (unsigned)h2 | ((unsigned)h3 << 16);
      *(uint2*)(qkhi + h * 136 + cb) = w0;
      unsigned short e0 = f2bf(aa0 - bf2f(h0)), e1 = f2bf(aa1 - bf2f(h1));
      unsigned short e2 = f2bf(aa2 - bf2f(h2)), e3 = f2bf(aa3 - bf2f(h3));
      uint2 w1; w1.x = (unsigned)e0 | ((unsigned)e1 << 16); w1.y = (unsigned)e2 | ((unsigned)e3 << 16);
      *(uint2*)(qklo + h * 136 + cb) = w1;
    }

    // stage 2: pos-enc + store gathered key features
    #pragma unroll
    for (int it = 0; it < 6; ++it){
      int e4 = (it * 256 + t) * 4;
      int k = e4 >> 7, c = e4 & 127;
      float r0 = rel[k * 3 + 0], r1 = rel[k * 3 + 1], r2 = rel[k * 3 + 2];
      float o[4];
      for (int u = 0; u < 4; ++u){
        float pe = fmaxf(r0 * wk3s[c + u] + r1 * wk3s[128 + c + u] + r2 * wk3s[256 + c + u] + bk3s[c + u], 0.f);
        o[u] = vbuf[it][u] + pe;
      }
      sts_bf4(kf + k * 136 + c, o);
    }
    __syncthreads();

    // ---- C: scores via MFMA (3 waves, one 16-key tile each) ----
    {
      int w = t >> 6, lane = t & 63, g = lane >> 4, cc = lane & 15;
      if (w < 3){
        int tile = w;
        const unsigned short* qh = qkhi + cc * 136;
        const unsigned short* ql = qklo + cc * 136;
        const unsigned short* kb = kf + (tile * 16 + cc) * 136 + g * 8;
        f32x4 acc = {0.f, 0.f, 0.f, 0.f};
        #pragma unroll
        for (int kk = 0; kk < 4; ++kk){
          bf16x8 ah = *(const bf16x8*)(qh + kk * 32 + g * 8);
          bf16x8 al = *(const bf16x8*)(ql + kk * 32 + g * 8);
          bf16x8 bb = *(const bf16x8*)(kb + kk * 32);
          acc = __builtin_amdgcn_mfma_f32_16x16x32_bf16(ah, bb, acc, 0, 0, 0);
          acc = __builtin_amdgcn_mfma_f32_16x16x32_bf16(al, bb, acc, 0, 0, 0);
        }
        if (lane < 32){
          int key = tile * 16 + cc;
          #pragma unroll
          for (int r = 0; r < 4; ++r){
            int h = g * 4 + r;
            sa[h * 52 + key] = acc[r] + sb8[p * 8 + h] + mb[key];
          }
        }
      }
    }
    __syncthreads();

    // ---- D: wave-parallel softmax + at-write (32 lanes) || A(p+1) (threads 64..111) ----
    if (t < 32){
      int h = t >> 2, sub = t & 3;
      float* s = sa + h * 52;
      float m = -1e30f;
      #pragma unroll
      for (int i = 0; i < 12; ++i) m = fmaxf(m, s[sub + 4 * i]);
      m = fmaxf(m, __shfl_xor(m, 1, 64));
      m = fmaxf(m, __shfl_xor(m, 2, 64));
      float e[12]; float den = 0.f;
      #pragma unroll
      for (int i = 0; i < 12; ++i){ float x = __expf(s[sub + 4 * i] - m); e[i] = x; den += x; }
      den += __shfl_xor(den, 1, 64);
      den += __shfl_xor(den, 2, 64);
      float rd = 1.f / den;
      #pragma unroll
      for (int i = 0; i < 12; ++i){
        int k = sub + 4 * i;
        float a = e[i] * rd;
        if (k >= 16 && k < 32) a *= 0.5f;   // E double-counts k in [16,32)
        unsigned short hi = f2bf(a);
        athi[h * 48 + k] = hi;
        atlo[h * 48 + k] = f2bf(a - bf2f(hi));
      }
    } else if (t >= 64 && t < 112 && p < 7){
      doA(t - 64, p + 1);
    }
    __syncthreads();

    // ---- E: af via MFMA (4 waves, 2 c-tiles each; af overwrites qk region, dead) ----
    {
      int w = t >> 6, lane = t & 63, g = lane >> 4, cc = lane & 15;
      int T0 = w * 2;
      const unsigned short* A0 = athi + cc * 48;
      const unsigned short* A1 = atlo + cc * 48;
      bf16x8 a1h = *(const bf16x8*)(A0 + g * 8);        // k = 8g..8g+7
      bf16x8 a1l = *(const bf16x8*)(A1 + g * 8);
      bf16x8 a2h = *(const bf16x8*)(A0 + 16 + g * 8);   // k = 16+8g..16+8g+7
      bf16x8 a2l = *(const bf16x8*)(A1 + 16 + g * 8);
      for (int T = T0; T < T0 + 2; ++T){
        int c = T * 16 + cc;
        bf16x8 b1, b2;
        #pragma unroll
        for (int j = 0; j < 8; ++j){
          b1[j] = (short)kf[(g * 8 + j) * 136 + c];
          b2[j] = (short)kf[(16 + g * 8 + j) * 136 + c];
        }
        f32x4 acc = {0.f, 0.f, 0.f, 0.f};
        acc = __builtin_amdgcn_mfma_f32_16x16x32_bf16(a1h, b1, acc, 0, 0, 0);
        acc = __builtin_amdgcn_mfma_f32_16x16x32_bf16(a1l, b1, acc, 0, 0, 0);
        acc = __builtin_amdgcn_mfma_f32_16x16x32_bf16(a2h, b2, acc, 0, 0, 0);
        acc = __builtin_amdgcn_mfma_f32_16x16x32_bf16(a2l, b2, acc, 0, 0, 0);
        if (lane < 32){
          #pragma unroll
          for (int r = 0; r < 4; ++r){
            int h = g * 4 + r;
            af[h * 132 + c] = acc[r];
          }
        }
      }
    }
    __syncthreads();

    // ---- F: V-proj half-partials ----
    {
      int j = t & 127, half = t >> 7, h = j >> 4;
      float acca = 0.f;
      int c0 = half * 64;
      for (int c = c0; c < c0 + 64; c += 4){
        float w[4];
        vload4<MODE>(w, ipw, (size_t)(256 + j) * CH + c);
        acca += af[h * 132 + c + 0] * w[0] + af[h * 132 + c + 1] * w[1]
              + af[h * 132 + c + 2] * w[2] + af[h * 132 + c + 3] * w[3];
      }
      sa[half * 128 + j] = acca;
    }
    __syncthreads();
  }

  // G(7): last query's O write
  if (t < 128){
    float o = sa[t] + sa[128 + t] + ld1<MODE>(ipb, 256 + t);
    O[(size_t)(qbase + 7) * CH + t] = f2bf(o);
  }
}

__global__ __launch_bounds__(256, 5) void attn_k(
  const void* vf, const void* vc, const void* qc,
  const void* wq3, const void* bq3, const void* wk3, const void* bk3,
  const void* ipw, const void* ipb,
  const int* kidx, const void* kmask,
  unsigned short* O, const int* hdr)
{
  __shared__ __attribute__((aligned(16))) char pool[29728];
  int mode = hdr[0], fmt = hdr[1];
  if (mode) attn_body<1>(pool, vf, vc, qc, wq3, bq3, wk3, bk3, ipw, ipb, kidx, kmask, O, fmt);
  else      attn_body<0>(pool, vf, vc, qc, wq3, bq3, wk3, bk3, ipw, ipb, kidx, kmask, O, fmt);
}

// ---------------- fused outproj + FFN + BN1 stats: 16 rows/block, 1250 blocks (R7-verbatim) ----------------
template<int MODE>
__device__ void opffn_body(char* pool, const unsigned short* SRC, unsigned short* DST,
    const void* outw, const void* outb, const void* w1, const void* b1,
    const void* w2, const void* b2, float* stats1)
{
  float* Os = (float*)pool;
  float* Hs = (float*)(pool + 8192);
  float* ssum = (float*)(pool + 24576);
  float* ssq  = (float*)(pool + 25088);
  int tid = threadIdx.x;
  int mbase = blockIdx.x * 16;

  for (int i = 0; i < 2; ++i){
    int idx4 = (tid + i * 256) * 4;
    int r = idx4 >> 7, c = idx4 & 127;
    lds_bf4(Os + idx4, SRC + (size_t)(mbase + r) * 128 + c);
  }
  if (tid < 128){ ssum[tid] = 0.f; ssq[tid] = 0.f; }
  __syncthreads();

  int j = tid & 127, rh = tid >> 7;
  float acc[8];
  for (int r = 0; r < 8; ++r) acc[r] = 0.f;
  for (int c = 0; c < 128; c += 4){
    float w4[4];
    vload4<MODE>(w4, outw, (size_t)j * 128 + c);
    for (int r = 0; r < 8; ++r){
      float4 o4 = *(const float4*)&Os[(rh * 8 + r) * 128 + c];
      acc[r] += o4.x * w4[0] + o4.y * w4[1] + o4.z * w4[2] + o4.w * w4[3];
    }
  }
  float bbo = ld1<MODE>(outb, j);
  __syncthreads();
  for (int r = 0; r < 8; ++r) Os[(rh * 8 + r) * 128 + j] = acc[r] + bbo;   // X1 f32
  __syncthreads();

  {
    float a[16];
    for (int r = 0; r < 16; ++r) a[r] = 0.f;
    for (int c = 0; c < 128; c += 4){
      float wv[4];
      for (int u = 0; u < 4; ++u) wv[u] = ld1<MODE>(w1, (size_t)(c + u) * 256 + tid);
      for (int r = 0; r < 16; ++r){
        float4 o4 = *(const float4*)&Os[r * 128 + c];
        a[r] += o4.x * wv[0] + o4.y * wv[1] + o4.z * wv[2] + o4.w * wv[3];
      }
    }
    float bb1 = ld1<MODE>(b1, tid);
    for (int r = 0; r < 16; ++r) Hs[r * 256 + tid] = fmaxf(a[r] + bb1, 0.f);
  }
  __syncthreads();

  int col = tid & 127;
  float a2[8];
  for (int r = 0; r < 8; ++r) a2[r] = 0.f;
  for (int jj = 0; jj < 256; jj += 4){
    float wv[4];
    for (int u = 0; u < 4; ++u) wv[u] = ld1<MODE>(w2, (size_t)(jj + u) * 128 + col);
    for (int r = 0; r < 8; ++r){
      float4 h4 = *(const float4*)&Hs[(rh * 8 + r) * 256 + jj];
      a2[r] += h4.x * wv[0] + h4.y * wv[1] + h4.z * wv[2] + h4.w * wv[3];
    }
  }
  float bb2 = ld1<MODE>(b2, col);
  float ls = 0.f, lq = 0.f;
  for (int r = 0; r < 8; ++r){
    float x = a2[r] + bb2 + Os[(rh * 8 + r) * 128 + col];
    DST[(size_t)(mbase + rh * 8 + r) * 128 + col] = f2bf(x);
    ls += x; lq += x * x;
  }
  atomicAdd(&ssum[col], ls);
  atomicAdd(&ssq[col], lq);
  __syncthreads();
  if (tid < 128){
    float* bank = stats1 + (size_t)(blockIdx.x & 7) * 256;
    atomicAdd(bank + tid, ssum[tid]);
    atomicAdd(bank + 128 + tid, ssq[tid]);
  }
}

__global__ __launch_bounds__(256) void opffn_k(const unsigned short* SRC, unsigned short* DST,
    const void* outw, const void* outb, const void* w1, const void* b1,
    const void* w2, const void* b2, float* stats1, const int* hdr)
{
  __shared__ __attribute__((aligned(16))) char pool[25600];
  if (hdr[0]) opffn_body<1>(pool, SRC, DST, outw, outb, w1, b1, w2, b2, stats1);
  else        opffn_body<0>(pool, SRC, DST, outw, outb, w1, b1, w2, b2, stats1);
}

// ------- head: 16 rows/block, 1250 blocks (R7-verbatim) -------
template<int MODE>
__device__ void head_body(char* pool, unsigned short* AD, const float* stats1,
    const void* g1, const void* be1, const void* wout, const void* bout, float* stats2)
{
  float* s1 = (float*)pool;
  float* t1 = (float*)(pool + 512);
  float* Xs = (float*)(pool + 1024);
  float* ssum = (float*)(pool + 9216);
  float* ssq  = (float*)(pool + 9728);
  int tid = threadIdx.x;
  int mbase = blockIdx.x * 16;
  if (tid < 128){
    float s = 0.f, sq = 0.f;
    for (int b = 0; b < 8; ++b){ s += stats1[b * 256 + tid]; sq += stats1[b * 256 + 128 + tid]; }
    float m = s * (1.f / 20000.f);
    float var = sq * (1.f / 20000.f) - m * m;
    float sc = ld1<MODE>(g1, tid) * rsqrtf(var + 1e-5f);
    s1[tid] = sc;
    t1[tid] = ld1<MODE>(be1, tid) - m * sc;
    ssum[tid] = 0.f; ssq[tid] = 0.f;
  }
  __syncthreads();
  for (int i = 0; i < 2; ++i){
    int idx4 = (tid + i * 256) * 4;
    int r = idx4 >> 7, c = idx4 & 127;
    float v[4];
    lds_bf4(v, AD + (size_t)(mbase + r) * 128 + c);
    Xs[idx4 + 0] = s1[c + 0] * v[0] + t1[c + 0];
    Xs[idx4 + 1] = s1[c + 1] * v[1] + t1[c + 1];
    Xs[idx4 + 2] = s1[c + 2] * v[2] + t1[c + 2];
    Xs[idx4 + 3] = s1[c + 3] * v[3] + t1[c + 3];
  }
  __syncthreads();
  int tcol = tid & 127, rh = tid >> 7;
  float acc[8];
  for (int r = 0; r < 8; ++r) acc[r] = 0.f;
  for (int k = 0; k < 128; k += 4){
    float wv[4];
    for (int u = 0; u < 4; ++u) wv[u] = ld1<MODE>(wout, (size_t)(k + u) * 128 + tcol);
    for (int r = 0; r < 8; ++r){
      float4 x4 = *(const float4*)&Xs[(rh * 8 + r) * 128 + k];
      acc[r] += x4.x * wv[0] + x4.y * wv[1] + x4.z * wv[2] + x4.w * wv[3];
    }
  }
  float bb = ld1<MODE>(bout, tcol);
  float ls = 0.f, lq = 0.f;
  for (int r = 0; r < 8; ++r){
    float z = acc[r] + bb;
    AD[(size_t)(mbase + rh * 8 + r) * 128 + tcol] = f2bf(z);
    ls += z; lq += z * z;
  }
  atomicAdd(&ssum[tcol], ls);
  atomicAdd(&ssq[tcol], lq);
  __syncthreads();
  if (tid < 128){
    float* bank = stats2 + (size_t)(blockIdx.x & 7) * 256;
    atomicAdd(bank + tid, ssum[tid]);
    atomicAdd(bank + 128 + tid, ssq[tid]);
  }
}

__global__ __launch_bounds__(256) void head_k(unsigned short* AD, const float* stats1,
    const void* g1, const void* be1, const void* wout, const void* bout,
    float* stats2, const int* hdr)
{
  __shared__ __attribute__((aligned(16))) char pool[10240];
  if (hdr[0]) head_body<1>(pool, AD, stats1, g1, be1, wout, bout, stats2);
  else        head_body<0>(pool, AD, stats1, g1, be1, wout, bout, stats2);
}

// ---------------- BN2 + relu: arena -> d_out ----------------
template<int MODE>
__device__ void bn2_body(float* ss, float* tt, const unsigned short* Z, void* out,
    const float* S2, const void* g2, const void* be2)
{
  int t = threadIdx.x;
  if (t < 128){
    float s = 0.f, sq = 0.f;
    for (int b = 0; b < 8; ++b){ s += S2[b * 256 + t]; sq += S2[b * 256 + 128 + t]; }
    float m = s * (1.f / 20000.f);
    float var = sq * (1.f / 20000.f) - m * m;
    float sc = ld1<MODE>(g2, t) * rsqrtf(var + 1e-5f);
    ss[t] = sc;
    tt[t] = ld1<MODE>(be2, t) - m * sc;
  }
  __syncthreads();
  size_t base = ((size_t)blockIdx.x * 256 + t) * 4;
  int c = (int)(base & 127);
  float v[4];
  lds_bf4(v, Z + base);
  float y0 = fmaxf(v[0] * ss[c + 0] + tt[c + 0], 0.f);
  float y1 = fmaxf(v[1] * ss[c + 1] + tt[c + 1], 0.f);
  float y2 = fmaxf(v[2] * ss[c + 2] + tt[c + 2], 0.f);
  float y3 = fmaxf(v[3] * ss[c + 3] + tt[c + 3], 0.f);
  if (MODE){
    float4 o; o.x = y0; o.y = y1; o.z = y2; o.w = y3;
    *(float4*)((float*)out + base) = o;
  } else {
    float yv[4] = {y0, y1, y2, y3};
    sts_bf4((unsigned short*)out + base, yv);
  }
}

__global__ __launch_bounds__(256) void bn2_k(const unsigned short* Z, void* out,
    const float* S2, const void* g2, const void* be2, const int* hdr)
{
  __shared__ float ss[128], tt[128];
  if (hdr[0]) bn2_body<1>(ss, tt, Z, out, S2, g2, be2);
  else        bn2_body<0>(ss, tt, Z, out, S2, g2, be2);
}

extern "C" void kernel_launch(void* const* d_in, const int* in_sizes, int n_in,
                              void* d_out, int out_size, void* d_ws, size_t ws_size,
                              hipStream_t stream)
{
  const void* vf    = d_in[0];
  const void* vc    = d_in[1];
  const void* qcrd  = d_in[2];
  const void* wq3   = d_in[3];
  const void* bq3   = d_in[4];
  const void* wk3   = d_in[5];
  const void* bk3   = d_in[6];
  const void* ipw   = d_in[7];
  const void* ipb   = d_in[8];
  const void* out_w = d_in[9];
  const void* out_b = d_in[10];
  const void* w1    = d_in[11];
  const void* b1    = d_in[12];
  const void* w2    = d_in[13];
  const void* b2    = d_in[14];
  const void* g1    = d_in[15];
  const void* be1   = d_in[16];
  const void* wout2 = d_in[17];
  const void* bout2 = d_in[18];
  const void* g2    = d_in[19];
  const void* be2   = d_in[20];
  const int*  kidx  = (const int*)d_in[21];
  const void* kmask = d_in[22];

  char* ws = (char*)d_ws;
  int*   hdr    = (int*)(ws + 0);
  float* stats1 = (float*)(ws + 1024);
  float* stats2 = (float*)(ws + 9216);

  unsigned short* O     = (unsigned short*)d_out;   // attn staging (bf16)
  unsigned short* arena = (unsigned short*)d_in[0]; // vf buffer: dead after attn

  hipMemsetAsync(ws, 0, 17408, stream);
  detect_k<<<1, 256, 0, stream>>>(qcrd, kmask, hdr);
  attn_k<<<2500, 256, 0, stream>>>(vf, vc, qcrd, wq3, bq3, wk3, bk3, ipw, ipb, kidx, kmask, O, hdr);
  opffn_k<<<1250, 256, 0, stream>>>(O, arena, out_w, out_b, w1, b1, w2, b2, stats1, hdr);
  head_k<<<1250, 256, 0, stream>>>(arena, stats1, g1, be1, wout2, bout2, stats2, hdr);
  bn2_k<<<2500, 256, 0, stream>>>(arena, d_out, stats2, g2, be2, hdr);
}

// Round 9
// 511.700 us; speedup vs baseline: 1.2165x; 1.2165x over previous
//
#include <hip/hip_runtime.h>
#include <stdint.h>

#define KNN 48
#define CH  128

typedef __attribute__((ext_vector_type(8))) short bf16x8;
typedef __attribute__((ext_vector_type(4))) float f32x4;

__device__ __forceinline__ float bf2f(unsigned short u){
  union { unsigned int i; float f; } v; v.i = ((unsigned int)u) << 16; return v.f;
}
__device__ __forceinline__ unsigned short f2bf(float f){
  union { float f; unsigned int i; } v; v.f = f;
  unsigned int x = v.i;
  x += 0x7fffu + ((x >> 16) & 1u);
  return (unsigned short)(x >> 16);
}
template<int MODE>
__device__ __forceinline__ float ld1(const void* p, size_t i){
  if (MODE) return ((const float*)p)[i];
  return bf2f(((const unsigned short*)p)[i]);
}
template<int MODE>
__device__ __forceinline__ void vload4(float* o, const void* p, size_t i){
  if (MODE){
    float4 v = *(const float4*)((const float*)p + i);
    o[0] = v.x; o[1] = v.y; o[2] = v.z; o[3] = v.w;
  } else {
    uint2 v = *(const uint2*)((const unsigned short*)p + i);
    union { unsigned int u; float f; } a, b, c, d;
    a.u = v.x << 16; b.u = v.x & 0xFFFF0000u;
    c.u = v.y << 16; d.u = v.y & 0xFFFF0000u;
    o[0] = a.f; o[1] = b.f; o[2] = c.f; o[3] = d.f;
  }
}
__device__ __forceinline__ void lds_bf4(float* o, const unsigned short* p){
  uint2 v = *(const uint2*)p;
  union { unsigned int u; float f; } a, b, c, d;
  a.u = v.x << 16; b.u = v.x & 0xFFFF0000u;
  c.u = v.y << 16; d.u = v.y & 0xFFFF0000u;
  o[0] = a.f; o[1] = b.f; o[2] = c.f; o[3] = d.f;
}
__device__ __forceinline__ void sts_bf4(unsigned short* p, const float* v){
  unsigned int lo = (unsigned int)f2bf(v[0]) | ((unsigned int)f2bf(v[1]) << 16);
  unsigned int hi = (unsigned int)f2bf(v[2]) | ((unsigned int)f2bf(v[3]) << 16);
  uint2 w; w.x = lo; w.y = hi;
  *(uint2*)p = w;
}

// ---------------- dtype + mask-format detector (parallel scan) ----------------
__global__ __launch_bounds__(256) void detect_k(const void* qc, const void* kmask, int* hdr){
  __shared__ int cnt, flg;
  int t = threadIdx.x;
  if (t == 0){ cnt = 0; flg = 0; }
  __syncthreads();
  float v = bf2f(((const unsigned short*)qc)[t]);
  if (v >= 0.f && v <= 70.5f) atomicAdd(&cnt, 1);
  const unsigned int* mw = (const unsigned int*)kmask;
  int f = 0;
  for (int i = t; i < 384; i += 256){
    unsigned int w = mw[i];
    if (w != 0u && w != 1u) f |= 1;
    if (w != 0u && w != 0x3F800000u) f |= 2;
    if (w == 0x3F800000u) f |= 4;
    unsigned int lo = w & 0xFFFFu, hi = w >> 16;
    if ((lo != 0u && lo != 0x3F80u) || (hi != 0u && hi != 0x3F80u)) f |= 8;
    if (lo == 0x3F80u || hi == 0x3F80u) f |= 16;
  }
  if (f) atomicOr(&flg, f);
  __syncthreads();
  if (t == 0){
    int F = flg;
    hdr[0] = (cnt >= 240) ? 0 : 1;
    int fmt;
    if (!(F & 2) && (F & 4)) fmt = 3;
    else if (!(F & 8) && (F & 16)) fmt = 2;
    else if (!(F & 1)) fmt = 0;
    else fmt = 1;
    hdr[1] = fmt;
  }
}

// ---------------- attention: 8 queries/block, 256 threads, 4 PAIR iterations ----------------
// R4 structure with D2 fused into the softmax wave (5 barriers/pair instead of 6).
// pool layout identical to R4 (rden2 slot retained but unused).
template<int MODE>
__device__ void attn_body(char* pool,
  const void* vf, const void* vc, const void* qc,
  const void* wq3, const void* bq3, const void* wk3, const void* bk3,
  const void* ipw, const void* ipb,
  const int* kidx, const void* kmask,
  unsigned short* O, int fmt)
{
  unsigned short* kf2 = (unsigned short*)(pool);
  float* qfv8 = (float*)(pool);
  unsigned short* qkhi = (unsigned short*)(pool + 26112);
  unsigned short* qklo = (unsigned short*)(pool + 30464);
  float* af   = (float*)(pool + 26112);
  float* sa2  = (float*)(pool + 34816);
  float* qv8  = (float*)(pool + 37888);
  float* wk3s = (float*)(pool + 42112);
  float* bk3s = (float*)(pool + 43648);
  float* sb8  = (float*)(pool + 44160);
  float* rel2 = (float*)(pool + 44416);
  float* mb2  = (float*)(pool + 45568);
  int*   idxs2= (int*)  (pool + 45952);
  float* qc8  = (float*)(pool + 46400);
  unsigned short* athi = (unsigned short*)(pool + 46496);
  unsigned short* atlo = (unsigned short*)(pool + 49568);

  int t = threadIdx.x;
  int qbase = blockIdx.x * 8;

  auto doA = [&](int tt, int pp){
    int q = tt / 48, kk = tt - q * 48;
    int n = qbase + 2 * pp + q;
    int iv = kidx[(size_t)n * KNN + kk];
    idxs2[q * 48 + kk] = iv;
    rel2[q * 144 + kk * 3 + 0] = ld1<MODE>(vc, (size_t)iv * 3 + 0) - qc8[(2 * pp + q) * 3 + 0];
    rel2[q * 144 + kk * 3 + 1] = ld1<MODE>(vc, (size_t)iv * 3 + 1) - qc8[(2 * pp + q) * 3 + 1];
    rel2[q * 144 + kk * 3 + 2] = ld1<MODE>(vc, (size_t)iv * 3 + 2) - qc8[(2 * pp + q) * 3 + 2];
    int mi = n * KNN + kk;
    int mval;
    if (fmt == 0)      mval = (((const int*)kmask)[mi] != 0);
    else if (fmt == 1) mval = (((const unsigned char*)kmask)[mi] != 0);
    else if (fmt == 2) mval = (((const unsigned short*)kmask)[mi] != 0);
    else               mval = (((const unsigned int*)kmask)[mi] != 0);
    mb2[q * 48 + kk] = mval ? -1e9f : 0.f;
  };

  for (int i = t; i < 384; i += 256) wk3s[i] = ld1<MODE>(wk3, i);
  if (t < 128) bk3s[t] = ld1<MODE>(bk3, t);
  if (t < 24)  qc8[t]  = ld1<MODE>(qc, (size_t)qbase * 3 + t);
  __syncthreads();

  if (t < 96) doA(t, 0);
  if (t < 128){
    float w0 = ld1<MODE>(wq3, t), w1 = ld1<MODE>(wq3, 128 + t);
    float w2 = ld1<MODE>(wq3, 256 + t), bb = ld1<MODE>(bq3, t);
    for (int q = 0; q < 8; ++q){
      float a = qc8[q * 3 + 0] * w0 + qc8[q * 3 + 1] * w1 + qc8[q * 3 + 2] * w2 + bb;
      qfv8[q * 132 + t] = fmaxf(a, 0.f);
    }
  }
  __syncthreads();

  {
    int j = t & 127, qg = (t >> 7) * 4;
    float a0 = 0.f, a1 = 0.f, a2 = 0.f, a3 = 0.f;
    for (int c = 0; c < 128; c += 4){
      float w[4];
      vload4<MODE>(w, ipw, (size_t)j * CH + c);
      for (int u = 0; u < 4; ++u){
        float wv = w[u];
        a0 += qfv8[(qg + 0) * 132 + c + u] * wv;
        a1 += qfv8[(qg + 1) * 132 + c + u] * wv;
        a2 += qfv8[(qg + 2) * 132 + c + u] * wv;
        a3 += qfv8[(qg + 3) * 132 + c + u] * wv;
      }
    }
    float bb = ld1<MODE>(ipb, j);
    qv8[(qg + 0) * 132 + j] = (a0 + bb) * 0.25f;
    qv8[(qg + 1) * 132 + j] = (a1 + bb) * 0.25f;
    qv8[(qg + 2) * 132 + j] = (a2 + bb) * 0.25f;
    qv8[(qg + 3) * 132 + j] = (a3 + bb) * 0.25f;
  }
  __syncthreads();

  for (int p = 0; p < 4; ++p){
    // ---- B: G(p-1) / sb8; gather loads issued EARLY (T14); qk-proj; gather finish ----
    if (p == 0){
      if (t < 64){
        int q = t >> 3, h = t & 7;
        float sb = 0.f;
        for (int d = 0; d < 16; ++d) sb += qv8[q * 132 + h * 16 + d] * ld1<MODE>(ipb, 128 + h * 16 + d);
        sb8[t] = sb;
      }
    } else {
      int q = t >> 7, j = t & 127;
      float o = sa2[q * 512 + j] + sa2[q * 512 + 128 + j] + ld1<MODE>(ipb, 256 + j);
      O[(size_t)(qbase + 2 * (p - 1) + q) * CH + j] = f2bf(o);
    }

    float vbuf[12][4];
    #pragma unroll
    for (int it = 0; it < 12; ++it){
      int e4 = (it * 256 + t) * 4;
      int q = (e4 >= 6144) ? 1 : 0;
      int r = e4 - q * 6144;
      int k = r >> 7, c = r & 127;
      int iv = idxs2[q * 48 + k];
      vload4<MODE>(vbuf[it], vf, (size_t)iv * CH + c);
    }

    {
      int h = t >> 5, cb = (t & 31) << 2;
      float aa0 = 0.f, aa1 = 0.f, aa2 = 0.f, aa3 = 0.f;
      float ab0 = 0.f, ab1 = 0.f, ab2 = 0.f, ab3 = 0.f;
      int qla = (2 * p) * 132 + h * 16, qlb = (2 * p + 1) * 132 + h * 16;
      for (int d = 0; d < 16; ++d){
        float w[4];
        vload4<MODE>(w, ipw, (size_t)(128 + h * 16 + d) * CH + cb);
        float qa = qv8[qla + d], qb = qv8[qlb + d];
        aa0 += qa * w[0]; aa1 += qa * w[1]; aa2 += qa * w[2]; aa3 += qa * w[3];
        ab0 += qb * w[0]; ab1 += qb * w[1]; ab2 += qb * w[2]; ab3 += qb * w[3];
      }
      unsigned short h0 = f2bf(aa0), h1 = f2bf(aa1), h2 = f2bf(aa2), h3 = f2bf(aa3);
      uint2 w0; w0.x = (unsigned)h0 | ((unsigned)h1 << 16); w0.y = (unsigned)h2 | ((unsigned)h3 << 16);
      *(uint2*)(qkhi + h * 136 + cb) = w0;
      unsigned short e0 = f2bf(aa0 - bf2f(h0)), e1 = f2bf(aa1 - bf2f(h1));
      unsigned short e2 = f2bf(aa2 - bf2f(h2)), e3 = f2bf(aa3 - bf2f(h3));
      uint2 w1; w1.x = (unsigned)e0 | ((unsigned)e1 << 16); w1.y = (unsigned)e2 | ((unsigned)e3 << 16);
      *(uint2*)(qklo + h * 136 + cb) = w1;
      unsigned short g0 = f2bf(ab0), g1 = f2bf(ab1), g2 = f2bf(ab2), g3 = f2bf(ab3);
      uint2 w2; w2.x = (unsigned)g0 | ((unsigned)g1 << 16); w2.y = (unsigned)g2 | ((unsigned)g3 << 16);
      *(uint2*)(qkhi + 1088 + h * 136 + cb) = w2;
      unsigned short f0 = f2bf(ab0 - bf2f(g0)), f1 = f2bf(ab1 - bf2f(g1));
      unsigned short f2 = f2bf(ab2 - bf2f(g2)), f3 = f2bf(ab3 - bf2f(g3));
      uint2 w3; w3.x = (unsigned)f0 | ((unsigned)f1 << 16); w3.y = (unsigned)f2 | ((unsigned)f3 << 16);
      *(uint2*)(qklo + 1088 + h * 136 + cb) = w3;
    }

    #pragma unroll
    for (int it = 0; it < 12; ++it){
      int e4 = (it * 256 + t) * 4;
      int q = (e4 >= 6144) ? 1 : 0;
      int r = e4 - q * 6144;
      int k = r >> 7, c = r & 127;
      float r0 = rel2[q * 144 + k * 3 + 0], r1 = rel2[q * 144 + k * 3 + 1], r2 = rel2[q * 144 + k * 3 + 2];
      float o[4];
      for (int u = 0; u < 4; ++u){
        float pe = fmaxf(r0 * wk3s[c + u] + r1 * wk3s[128 + c + u] + r2 * wk3s[256 + c + u] + bk3s[c + u], 0.f);
        o[u] = vbuf[it][u] + pe;
      }
      sts_bf4(kf2 + q * 6528 + k * 136 + c, o);
    }
    __syncthreads();

    // ---- C: scores via MFMA (R4-verbatim) ----
    {
      int w = t >> 6, lane = t & 63, g = lane >> 4, cc = lane & 15;
      int q = w >> 1;
      int t0 = (w & 1) ? 2 : 0, t1 = (w & 1) ? 3 : 2;
      const unsigned short* qh = qkhi + q * 1088 + cc * 136;
      const unsigned short* ql = qklo + q * 1088 + cc * 136;
      for (int tile = t0; tile < t1; ++tile){
        const unsigned short* kb = kf2 + q * 6528 + (tile * 16 + cc) * 136 + g * 8;
        f32x4 acc = {0.f, 0.f, 0.f, 0.f};
        #pragma unroll
        for (int kk = 0; kk < 4; ++kk){
          bf16x8 ah = *(const bf16x8*)(qh + kk * 32 + g * 8);
          bf16x8 al = *(const bf16x8*)(ql + kk * 32 + g * 8);
          bf16x8 bb = *(const bf16x8*)(kb + kk * 32);
          acc = __builtin_amdgcn_mfma_f32_16x16x32_bf16(ah, bb, acc, 0, 0, 0);
          acc = __builtin_amdgcn_mfma_f32_16x16x32_bf16(al, bb, acc, 0, 0, 0);
        }
        if (lane < 32){
          int key = tile * 16 + cc;
          #pragma unroll
          for (int r = 0; r < 4; ++r){
            int h = g * 4 + r;
            sa2[q * 416 + h * 52 + key] = acc[r] + sb8[(2 * p + q) * 8 + h] + mb2[q * 48 + key];
          }
        }
      }
    }
    __syncthreads();

    // ---- D: wave-parallel softmax FUSED with at-write (wave 0) || A(p+1) ----
    // (fused arithmetic validated by R8's passing refcheck)
    if (t < 64){
      int row = t >> 2, sub = t & 3;          // row = q*8 + h
      int q = row >> 3, h = row & 7;
      float* s = sa2 + q * 416 + h * 52;
      float m = -1e30f;
      #pragma unroll
      for (int i = 0; i < 12; ++i) m = fmaxf(m, s[sub + 4 * i]);
      m = fmaxf(m, __shfl_xor(m, 1, 64));
      m = fmaxf(m, __shfl_xor(m, 2, 64));
      float e[12]; float den = 0.f;
      #pragma unroll
      for (int i = 0; i < 12; ++i){ float x = __expf(s[sub + 4 * i] - m); e[i] = x; den += x; }
      den += __shfl_xor(den, 1, 64);
      den += __shfl_xor(den, 2, 64);
      float rd = 1.f / den;
      unsigned short* ah = athi + (q * 16 + h) * 48;
      unsigned short* al = atlo + (q * 16 + h) * 48;
      #pragma unroll
      for (int i = 0; i < 12; ++i){
        int k = sub + 4 * i;
        float a = e[i] * rd;
        if (k >= 16 && k < 32) a *= 0.5f;   // E double-counts k in [16,32)
        unsigned short hi = f2bf(a);
        ah[k] = hi;
        al[k] = f2bf(a - bf2f(hi));
      }
    } else if (t < 160 && p < 3){
      doA(t - 64, p + 1);
    }
    __syncthreads();

    // ---- E: af via MFMA (R4-verbatim; af overwrites qk region, dead) ----
    {
      int w = t >> 6, lane = t & 63, g = lane >> 4, cc = lane & 15;
      int q = w >> 1;
      int T0 = (w & 1) * 4;
      const unsigned short* A0 = athi + q * 768 + cc * 48;
      const unsigned short* A1 = atlo + q * 768 + cc * 48;
      bf16x8 a1h = *(const bf16x8*)(A0 + g * 8);
      bf16x8 a1l = *(const bf16x8*)(A1 + g * 8);
      bf16x8 a2h = *(const bf16x8*)(A0 + 16 + g * 8);
      bf16x8 a2l = *(const bf16x8*)(A1 + 16 + g * 8);
      const unsigned short* kq = kf2 + q * 6528;
      for (int T = 0; T < 4; ++T){
        int c = (T0 + T) * 16 + cc;
        bf16x8 b1, b2;
        #pragma unroll
        for (int j = 0; j < 8; ++j){
          b1[j] = (short)kq[(g * 8 + j) * 136 + c];
          b2[j] = (short)kq[(16 + g * 8 + j) * 136 + c];
        }
        f32x4 acc = {0.f, 0.f, 0.f, 0.f};
        acc = __builtin_amdgcn_mfma_f32_16x16x32_bf16(a1h, b1, acc, 0, 0, 0);
        acc = __builtin_amdgcn_mfma_f32_16x16x32_bf16(a1l, b1, acc, 0, 0, 0);
        acc = __builtin_amdgcn_mfma_f32_16x16x32_bf16(a2h, b2, acc, 0, 0, 0);
        acc = __builtin_amdgcn_mfma_f32_16x16x32_bf16(a2l, b2, acc, 0, 0, 0);
        if (lane < 32){
          #pragma unroll
          for (int r = 0; r < 4; ++r){
            int h = g * 4 + r;
            af[q * 1056 + h * 132 + c] = acc[r];
          }
        }
      }
    }
    __syncthreads();

    // ---- F: V-proj half-partials (R4-verbatim) ----
    {
      int j = t & 127, half = t >> 7, h = j >> 4;
      float acca = 0.f, accb = 0.f;
      int c0 = half * 64;
      for (int c = c0; c < c0 + 64; c += 4){
        float w[4];
        vload4<MODE>(w, ipw, (size_t)(256 + j) * CH + c);
        acca += af[h * 132 + c + 0] * w[0] + af[h * 132 + c + 1] * w[1]
              + af[h * 132 + c + 2] * w[2] + af[h * 132 + c + 3] * w[3];
        accb += af[1056 + h * 132 + c + 0] * w[0] + af[1056 + h * 132 + c + 1] * w[1]
              + af[1056 + h * 132 + c + 2] * w[2] + af[1056 + h * 132 + c + 3] * w[3];
      }
      sa2[half * 128 + j] = acca;
      sa2[512 + half * 128 + j] = accb;
    }
    __syncthreads();
  }

  {
    int q = t >> 7, j = t & 127;
    float o = sa2[q * 512 + j] + sa2[q * 512 + 128 + j] + ld1<MODE>(ipb, 256 + j);
    O[(size_t)(qbase + 6 + q) * CH + j] = f2bf(o);
  }
}

__global__ __launch_bounds__(256, 3) void attn_k(
  const void* vf, const void* vc, const void* qc,
  const void* wq3, const void* bq3, const void* wk3, const void* bk3,
  const void* ipw, const void* ipb,
  const int* kidx, const void* kmask,
  unsigned short* O, const int* hdr)
{
  __shared__ __attribute__((aligned(16))) char pool[52640];
  int mode = hdr[0], fmt = hdr[1];
  if (mode) attn_body<1>(pool, vf, vc, qc, wq3, bq3, wk3, bk3, ipw, ipb, kidx, kmask, O, fmt);
  else      attn_body<0>(pool, vf, vc, qc, wq3, bq3, wk3, bk3, ipw, ipb, kidx, kmask, O, fmt);
}

// ---------------- fused outproj + FFN + BN1 stats: 16 rows/block, 1250 blocks (R7-verbatim) ----------------
template<int MODE>
__device__ void opffn_body(char* pool, const unsigned short* SRC, unsigned short* DST,
    const void* outw, const void* outb, const void* w1, const void* b1,
    const void* w2, const void* b2, float* stats1)
{
  float* Os = (float*)pool;
  float* Hs = (float*)(pool + 8192);
  float* ssum = (float*)(pool + 24576);
  float* ssq  = (float*)(pool + 25088);
  int tid = threadIdx.x;
  int mbase = blockIdx.x * 16;

  for (int i = 0; i < 2; ++i){
    int idx4 = (tid + i * 256) * 4;
    int r = idx4 >> 7, c = idx4 & 127;
    lds_bf4(Os + idx4, SRC + (size_t)(mbase + r) * 128 + c);
  }
  if (tid < 128){ ssum[tid] = 0.f; ssq[tid] = 0.f; }
  __syncthreads();

  int j = tid & 127, rh = tid >> 7;
  float acc[8];
  for (int r = 0; r < 8; ++r) acc[r] = 0.f;
  for (int c = 0; c < 128; c += 4){
    float w4[4];
    vload4<MODE>(w4, outw, (size_t)j * 128 + c);
    for (int r = 0; r < 8; ++r){
      float4 o4 = *(const float4*)&Os[(rh * 8 + r) * 128 + c];
      acc[r] += o4.x * w4[0] + o4.y * w4[1] + o4.z * w4[2] + o4.w * w4[3];
    }
  }
  float bbo = ld1<MODE>(outb, j);
  __syncthreads();
  for (int r = 0; r < 8; ++r) Os[(rh * 8 + r) * 128 + j] = acc[r] + bbo;   // X1 f32
  __syncthreads();

  {
    float a[16];
    for (int r = 0; r < 16; ++r) a[r] = 0.f;
    for (int c = 0; c < 128; c += 4){
      float wv[4];
      for (int u = 0; u < 4; ++u) wv[u] = ld1<MODE>(w1, (size_t)(c + u) * 256 + tid);
      for (int r = 0; r < 16; ++r){
        float4 o4 = *(const float4*)&Os[r * 128 + c];
        a[r] += o4.x * wv[0] + o4.y * wv[1] + o4.z * wv[2] + o4.w * wv[3];
      }
    }
    float bb1 = ld1<MODE>(b1, tid);
    for (int r = 0; r < 16; ++r) Hs[r * 256 + tid] = fmaxf(a[r] + bb1, 0.f);
  }
  __syncthreads();

  int col = tid & 127;
  float a2[8];
  for (int r = 0; r < 8; ++r) a2[r] = 0.f;
  for (int jj = 0; jj < 256; jj += 4){
    float wv[4];
    for (int u = 0; u < 4; ++u) wv[u] = ld1<MODE>(w2, (size_t)(jj + u) * 128 + col);
    for (int r = 0; r < 8; ++r){
      float4 h4 = *(const float4*)&Hs[(rh * 8 + r) * 256 + jj];
      a2[r] += h4.x * wv[0] + h4.y * wv[1] + h4.z * wv[2] + h4.w * wv[3];
    }
  }
  float bb2 = ld1<MODE>(b2, col);
  float ls = 0.f, lq = 0.f;
  for (int r = 0; r < 8; ++r){
    float x = a2[r] + bb2 + Os[(rh * 8 + r) * 128 + col];
    DST[(size_t)(mbase + rh * 8 + r) * 128 + col] = f2bf(x);
    ls += x; lq += x * x;
  }
  atomicAdd(&ssum[col], ls);
  atomicAdd(&ssq[col], lq);
  __syncthreads();
  if (tid < 128){
    float* bank = stats1 + (size_t)(blockIdx.x & 7) * 256;
    atomicAdd(bank + tid, ssum[tid]);
    atomicAdd(bank + 128 + tid, ssq[tid]);
  }
}

__global__ __launch_bounds__(256) void opffn_k(const unsigned short* SRC, unsigned short* DST,
    const void* outw, const void* outb, const void* w1, const void* b1,
    const void* w2, const void* b2, float* stats1, const int* hdr)
{
  __shared__ __attribute__((aligned(16))) char pool[25600];
  if (hdr[0]) opffn_body<1>(pool, SRC, DST, outw, outb, w1, b1, w2, b2, stats1);
  else        opffn_body<0>(pool, SRC, DST, outw, outb, w1, b1, w2, b2, stats1);
}

// ------- head: 16 rows/block, 1250 blocks (R7-verbatim) -------
template<int MODE>
__device__ void head_body(char* pool, unsigned short* AD, const float* stats1,
    const void* g1, const void* be1, const void* wout, const void* bout, float* stats2)
{
  float* s1 = (float*)pool;
  float* t1 = (float*)(pool + 512);
  float* Xs = (float*)(pool + 1024);
  float* ssum = (float*)(pool + 9216);
  float* ssq  = (float*)(pool + 9728);
  int tid = threadIdx.x;
  int mbase = blockIdx.x * 16;
  if (tid < 128){
    float s = 0.f, sq = 0.f;
    for (int b = 0; b < 8; ++b){ s += stats1[b * 256 + tid]; sq += stats1[b * 256 + 128 + tid]; }
    float m = s * (1.f / 20000.f);
    float var = sq * (1.f / 20000.f) - m * m;
    float sc = ld1<MODE>(g1, tid) * rsqrtf(var + 1e-5f);
    s1[tid] = sc;
    t1[tid] = ld1<MODE>(be1, tid) - m * sc;
    ssum[tid] = 0.f; ssq[tid] = 0.f;
  }
  __syncthreads();
  for (int i = 0; i < 2; ++i){
    int idx4 = (tid + i * 256) * 4;
    int r = idx4 >> 7, c = idx4 & 127;
    float v[4];
    lds_bf4(v, AD + (size_t)(mbase + r) * 128 + c);
    Xs[idx4 + 0] = s1[c + 0] * v[0] + t1[c + 0];
    Xs[idx4 + 1] = s1[c + 1] * v[1] + t1[c + 1];
    Xs[idx4 + 2] = s1[c + 2] * v[2] + t1[c + 2];
    Xs[idx4 + 3] = s1[c + 3] * v[3] + t1[c + 3];
  }
  __syncthreads();
  int tcol = tid & 127, rh = tid >> 7;
  float acc[8];
  for (int r = 0; r < 8; ++r) acc[r] = 0.f;
  for (int k = 0; k < 128; k += 4){
    float wv[4];
    for (int u = 0; u < 4; ++u) wv[u] = ld1<MODE>(wout, (size_t)(k + u) * 128 + tcol);
    for (int r = 0; r < 8; ++r){
      float4 x4 = *(const float4*)&Xs[(rh * 8 + r) * 128 + k];
      acc[r] += x4.x * wv[0] + x4.y * wv[1] + x4.z * wv[2] + x4.w * wv[3];
    }
  }
  float bb = ld1<MODE>(bout, tcol);
  float ls = 0.f, lq = 0.f;
  for (int r = 0; r < 8; ++r){
    float z = acc[r] + bb;
    AD[(size_t)(mbase + rh * 8 + r) * 128 + tcol] = f2bf(z);
    ls += z; lq += z * z;
  }
  atomicAdd(&ssum[tcol], ls);
  atomicAdd(&ssq[tcol], lq);
  __syncthreads();
  if (tid < 128){
    float* bank = stats2 + (size_t)(blockIdx.x & 7) * 256;
    atomicAdd(bank + tid, ssum[tid]);
    atomicAdd(bank + 128 + tid, ssq[tid]);
  }
}

__global__ __launch_bounds__(256) void head_k(unsigned short* AD, const float* stats1,
    const void* g1, const void* be1, const void* wout, const void* bout,
    float* stats2, const int* hdr)
{
  __shared__ __attribute__((aligned(16))) char pool[10240];
  if (hdr[0]) head_body<1>(pool, AD, stats1, g1, be1, wout, bout, stats2);
  else        head_body<0>(pool, AD, stats1, g1, be1, wout, bout, stats2);
}

// ---------------- BN2 + relu: arena -> d_out ----------------
template<int MODE>
__device__ void bn2_body(float* ss, float* tt, const unsigned short* Z, void* out,
    const float* S2, const void* g2, const void* be2)
{
  int t = threadIdx.x;
  if (t < 128){
    float s = 0.f, sq = 0.f;
    for (int b = 0; b < 8; ++b){ s += S2[b * 256 + t]; sq += S2[b * 256 + 128 + t]; }
    float m = s * (1.f / 20000.f);
    float var = sq * (1.f / 20000.f) - m * m;
    float sc = ld1<MODE>(g2, t) * rsqrtf(var + 1e-5f);
    ss[t] = sc;
    tt[t] = ld1<MODE>(be2, t) - m * sc;
  }
  __syncthreads();
  size_t base = ((size_t)blockIdx.x * 256 + t) * 4;
  int c = (int)(base & 127);
  float v[4];
  lds_bf4(v, Z + base);
  float y0 = fmaxf(v[0] * ss[c + 0] + tt[c + 0], 0.f);
  float y1 = fmaxf(v[1] * ss[c + 1] + tt[c + 1], 0.f);
  float y2 = fmaxf(v[2] * ss[c + 2] + tt[c + 2], 0.f);
  float y3 = fmaxf(v[3] * ss[c + 3] + tt[c + 3], 0.f);
  if (MODE){
    float4 o; o.x = y0; o.y = y1; o.z = y2; o.w = y3;
    *(float4*)((float*)out + base) = o;
  } else {
    float yv[4] = {y0, y1, y2, y3};
    sts_bf4((unsigned short*)out + base, yv);
  }
}

__global__ __launch_bounds__(256) void bn2_k(const unsigned short* Z, void* out,
    const float* S2, const void* g2, const void* be2, const int* hdr)
{
  __shared__ float ss[128], tt[128];
  if (hdr[0]) bn2_body<1>(ss, tt, Z, out, S2, g2, be2);
  else        bn2_body<0>(ss, tt, Z, out, S2, g2, be2);
}

extern "C" void kernel_launch(void* const* d_in, const int* in_sizes, int n_in,
                              void* d_out, int out_size, void* d_ws, size_t ws_size,
                              hipStream_t stream)
{
  const void* vf    = d_in[0];
  const void* vc    = d_in[1];
  const void* qcrd  = d_in[2];
  const void* wq3   = d_in[3];
  const void* bq3   = d_in[4];
  const void* wk3   = d_in[5];
  const void* bk3   = d_in[6];
  const void* ipw   = d_in[7];
  const void* ipb   = d_in[8];
  const void* out_w = d_in[9];
  const void* out_b = d_in[10];
  const void* w1    = d_in[11];
  const void* b1    = d_in[12];
  const void* w2    = d_in[13];
  const void* b2    = d_in[14];
  const void* g1    = d_in[15];
  const void* be1   = d_in[16];
  const void* wout2 = d_in[17];
  const void* bout2 = d_in[18];
  const void* g2    = d_in[19];
  const void* be2   = d_in[20];
  const int*  kidx  = (const int*)d_in[21];
  const void* kmask = d_in[22];

  char* ws = (char*)d_ws;
  int*   hdr    = (int*)(ws + 0);
  float* stats1 = (float*)(ws + 1024);
  float* stats2 = (float*)(ws + 9216);

  unsigned short* O     = (unsigned short*)d_out;   // attn staging (bf16)
  unsigned short* arena = (unsigned short*)d_in[0]; // vf buffer: dead after attn

  hipMemsetAsync(ws, 0, 17408, stream);
  detect_k<<<1, 256, 0, stream>>>(qcrd, kmask, hdr);
  attn_k<<<2500, 256, 0, stream>>>(vf, vc, qcrd, wq3, bq3, wk3, bk3, ipw, ipb, kidx, kmask, O, hdr);
  opffn_k<<<1250, 256, 0, stream>>>(O, arena, out_w, out_b, w1, b1, w2, b2, stats1, hdr);
  head_k<<<1250, 256, 0, stream>>>(arena, stats1, g1, be1, wout2, bout2, stats2, hdr);
  bn2_k<<<2500, 256, 0, stream>>>(arena, d_out, stats2, g2, be2, hdr);
}